// Round 9
// baseline (411.126 us; speedup 1.0000x reference)
//
#include <hip/hip_runtime.h>
#include <hip/hip_bf16.h>

#define NN 8192
#define DD 128

typedef __attribute__((ext_vector_type(8))) short short8;
typedef __attribute__((ext_vector_type(4))) float f32x4;
typedef __attribute__((ext_vector_type(4))) int i32x4;
typedef unsigned int u32;
typedef unsigned long long u64;

__device__ __forceinline__ ushort f2bf(float f) {
    __hip_bfloat16 h = __float2bfloat16(f);
    return *(ushort*)&h;
}

// async 16B/lane global->LDS; LDS dest must be wave-uniform base + lane*16.
__device__ __forceinline__ void async_ld16(const void* g, void* l) {
    __builtin_amdgcn_global_load_lds(
        (const __attribute__((address_space(1))) u32*)g,
        (__attribute__((address_space(3))) u32*)l, 16, 0, 0);
}

#define PACK4(b, v, sh)                                     \
    b |= (u32)((v).x & 1) << (sh);                          \
    b |= (u32)((v).y & 1) << ((sh) + 1);                    \
    b |= (u32)((v).z & 1) << ((sh) + 2);                    \
    b |= (u32)((v).w & 1) << ((sh) + 3);

// ---------------- K3a: deep-pipelined A bit-pack ----------------
// Thread T -> (row = T>>6, kb = (T&63)>>2, kg = T&3): packs the 16 8-col
// chunks k = kb*512 + kt*64 + tp*32 + kg*8 (kt 0..7, tp 0..1) into one uint4,
// byte index j = kt*2+tp, bit u = col +u. 16 independent int4 loads issued
// per half before first use -> ~256B/lane in flight, HBM-saturating.
// Store: lanes of a wave share a row, q=lane -> 1KB contiguous per wave.
__global__ __launch_bounds__(256) void k3a_pack(const int* __restrict__ A,
                                                uint4* __restrict__ Ap) {
    u32 T = blockIdx.x * 256 + threadIdx.x;   // 0..524287
    u32 row = T >> 6, q = T & 63, kb = q >> 2, kg = q & 3;
    const int* base = A + (size_t)row * NN + kb * 512 + kg * 8;
    u32 d[4];
#pragma unroll
    for (int h = 0; h < 2; ++h) {             // kt 0..3 then 4..7
        i32x4 v[16];
#pragma unroll
        for (int j = 0; j < 8; ++j) {         // j = local (kt-4h)*2+tp
            int kt = h * 4 + (j >> 1), tp = j & 1;
            const int* p = base + kt * 64 + tp * 32;
            v[j * 2]     = __builtin_nontemporal_load((const i32x4*)p);
            v[j * 2 + 1] = __builtin_nontemporal_load((const i32x4*)(p + 4));
        }
        u32 b01 = 0, b23 = 0;
#pragma unroll
        for (int j = 0; j < 8; ++j) {
            u32 b = 0;
            PACK4(b, v[j * 2], 0);
            PACK4(b, v[j * 2 + 1], 4);
            if (j < 4) b01 |= b << (8 * j);
            else       b23 |= b << (8 * (j - 4));
        }
        d[h * 2] = b01; d[h * 2 + 1] = b23;
    }
    Ap[T] = make_uint4(d[0], d[1], d[2], d[3]);
}

// ---------------- K12: Wh = X @ Ws fused with per-row scalars + bf16 transpose ----
__global__ __launch_bounds__(256) void k12_gemm(const float* __restrict__ X,
                                                const float* __restrict__ Ws,
                                                const float* __restrict__ a,
                                                ushort* __restrict__ WhT,
                                                float* __restrict__ C1,
                                                float* __restrict__ C1s,
                                                float2* __restrict__ E2) {
    __shared__ float lWs[128 * 132];   // [k][c] pad 132
    __shared__ float lX[32 * 132];     // [r][c] pad 132
    __shared__ ushort lT2[128 * 32];   // [c][r] bf16 transpose staging
    __shared__ float la[256];
    int t = threadIdx.x, bx = blockIdx.x;
    la[t] = a[t];
    const float4* Ws4 = (const float4*)Ws;
    const float4* X4 = (const float4*)X;
    for (int j = 0; j < 16; ++j) {
        int u = j * 256 + t;
        int k = u >> 5, c4 = u & 31;
        *(float4*)&lWs[k * 132 + c4 * 4] = Ws4[u];
    }
    for (int j = 0; j < 4; ++j) {
        int u = j * 256 + t;
        int r = u >> 5, c4 = u & 31;
        *(float4*)&lX[r * 132 + c4 * 4] = X4[bx * 1024 + u];
    }
    __syncthreads();
    int r0 = (t >> 5) * 4, c0 = (t & 31) * 4;
    float acc[4][4];
#pragma unroll
    for (int i = 0; i < 4; ++i)
#pragma unroll
        for (int j = 0; j < 4; ++j) acc[i][j] = 0.f;
#pragma unroll 4
    for (int k = 0; k < 128; ++k) {
        float4 wv = *(const float4*)&lWs[k * 132 + c0];
        float x0 = lX[(r0 + 0) * 132 + k];
        float x1 = lX[(r0 + 1) * 132 + k];
        float x2 = lX[(r0 + 2) * 132 + k];
        float x3 = lX[(r0 + 3) * 132 + k];
#pragma unroll
        for (int j = 0; j < 4; ++j) {
            acc[0][j] += x0 * ((const float*)&wv)[j];
            acc[1][j] += x1 * ((const float*)&wv)[j];
            acc[2][j] += x2 * ((const float*)&wv)[j];
            acc[3][j] += x3 * ((const float*)&wv)[j];
        }
    }
#pragma unroll
    for (int i = 0; i < 4; ++i)
#pragma unroll
        for (int j = 0; j < 4; ++j)
            lT2[(c0 + j) * 32 + r0 + i] = f2bf(acc[i][j]);
    float p1[4], p2[4];
#pragma unroll
    for (int i = 0; i < 4; ++i) {
        p1[i] = 0.f; p2[i] = 0.f;
#pragma unroll
        for (int j = 0; j < 4; ++j) {
            p1[i] += acc[i][j] * la[c0 + j];
            p2[i] += acc[i][j] * la[128 + c0 + j];
        }
    }
#pragma unroll
    for (int m = 1; m < 32; m <<= 1) {
#pragma unroll
        for (int i = 0; i < 4; ++i) {
            p1[i] += __shfl_xor(p1[i], m);
            p2[i] += __shfl_xor(p2[i], m);
        }
    }
    if ((t & 31) == 0) {
#pragma unroll
        for (int i = 0; i < 4; ++i) {
            int row = bx * 32 + r0 + i;
            C1[row]  = __expf(p1[i]);
            C1s[row] = __expf(0.2f * p1[i]);
            E2[row]  = make_float2(__expf(p2[i]), __expf(0.2f * p2[i]));
        }
    }
    __syncthreads();
    {
        int d = t >> 1, hf = t & 1;
        uint4* dst = (uint4*)&WhT[(size_t)d * NN + bx * 32 + hf * 16];
        const uint4* src = (const uint4*)&lT2[d * 32 + hf * 16];
        dst[0] = src[0];
        dst[1] = src[1];
    }
}

// ---------------- K3b: masked-softmax GEMM, zero loop-loads, zero loop-barriers --
// grid (32 rowblocks, 16 ksplit) x 512 thr (8 waves x 32 rows). B-slice
// (128 KB) + E-slice (4 KB) DMA'd once; masks = 2 uint4 REGISTERS per lane
// (coalesced prologue load from Ap, compile-time byte extraction). The fully
// unrolled kt-loop is pure {VALU af-build, ds_read B, MFMA}.
__global__ __launch_bounds__(512, 2) void k3b_main(
    const uint4* __restrict__ Ap, const ushort* __restrict__ WhT,
    const float* __restrict__ C1, const float* __restrict__ C1s,
    const float2* __restrict__ E2,
    float* __restrict__ Hp, float* __restrict__ Lp) {

    __shared__ __align__(16) char lB[131072];      // [p = kt*16+tp*8+c][lane*16]
    __shared__ __align__(16) char lE[4096];        // float2 E for 512 k

    int tid = threadIdx.x;
    int lane = tid & 63;
    int w = tid >> 6;           // 8 waves
    int n = lane & 15;
    int kg = lane >> 4;

    int bx = blockIdx.x;        // 32 row-blocks (256 rows each)
    int kb = blockIdx.y;        // 16 k-splits (512 k each)
    int rb = bx * 256 + w * 32; // wave's 32 rows (two 16-row groups)

    float c1_0 = C1[rb + n],      c1s_0 = C1s[rb + n];
    float c1_1 = C1[rb + 16 + n], c1s_1 = C1s[rb + 16 + n];

    // masks: lane (n,kg) -> rows rb+n, rb+16+n; one uint4 each
    uint4 Mq0 = Ap[(size_t)(rb + n) * 64 + kb * 4 + kg];
    uint4 Mq1 = Ap[(size_t)(rb + 16 + n) * 64 + kb * 4 + kg];

    // stage ENTIRE B-slice (128 fragments x 1 KB) -- wave w stages p = w+8i
#pragma unroll
    for (int i = 0; i < 16; ++i) {
        int p = w + i * 8;
        int kt = p >> 4, tp = (p >> 3) & 1, c = p & 7;
        const ushort* src = WhT + (size_t)(c * 16 + n) * NN +
                            (size_t)kb * 512 + kt * 64 + tp * 32 + kg * 8;
        async_ld16(src, lB + p * 1024 + lane * 16);
    }
    if (w == 0)
#pragma unroll
        for (int i = 0; i < 4; ++i)
            async_ld16((const char*)(E2 + (size_t)kb * 512) + (i * 64 + lane) * 16,
                       lE + (i * 64 + lane) * 16);

    short8 ones;
#pragma unroll
    for (int j = 0; j < 8; ++j) ones[j] = (short)0x3F80;  // bf16 1.0

    f32x4 acc0[8], acc1[8];
#pragma unroll
    for (int c = 0; c < 8; ++c) {
        acc0[c] = (f32x4){0.f, 0.f, 0.f, 0.f};
        acc1[c] = (f32x4){0.f, 0.f, 0.f, 0.f};
    }
    f32x4 accl0 = (f32x4){0.f, 0.f, 0.f, 0.f};
    f32x4 accl1 = (f32x4){0.f, 0.f, 0.f, 0.f};

    __syncthreads();   // the ONLY barrier: B/E LDS resident, read-only after

#pragma unroll
    for (int kt = 0; kt < 8; ++kt) {
#pragma unroll
        for (int tp = 0; tp < 2; ++tp) {
            const int j = kt * 2 + tp;   // compile-time byte index
            u32 d0 = (j < 4) ? Mq0.x : (j < 8) ? Mq0.y : (j < 12) ? Mq0.z : Mq0.w;
            u32 d1 = (j < 4) ? Mq1.x : (j < 8) ? Mq1.y : (j < 12) ? Mq1.z : Mq1.w;
            u32 ab0 = (d0 >> ((j & 3) * 8)) & 0xffu;
            u32 ab1 = (d1 >> ((j & 3) * 8)) & 0xffu;

            const float4* ev = (const float4*)((const float*)lE +
                                               (kt * 64 + tp * 32 + kg * 8) * 2);
            float pe[16];
            *(float4*)(pe + 0)  = ev[0];
            *(float4*)(pe + 4)  = ev[1];
            *(float4*)(pe + 8)  = ev[2];
            *(float4*)(pe + 12) = ev[3];
            short8 af0, af1;
#pragma unroll
            for (int u = 0; u < 8; ++u) {
                // exp(leaky(s1+s2)) = max(e^s1 e^s2, e^.2s1 e^.2s2)
                float w0 = fmaxf(c1_0 * pe[2 * u], c1s_0 * pe[2 * u + 1]);
                float w1 = fmaxf(c1_1 * pe[2 * u], c1s_1 * pe[2 * u + 1]);
                af0[u] = ((ab0 >> u) & 1u) ? (short)f2bf(w0) : (short)0;
                af1[u] = ((ab1 >> u) & 1u) ? (short)f2bf(w1) : (short)0;
            }
            const short8* bb = (const short8*)(lB + (kt * 16 + tp * 8) * 1024);
#pragma unroll
            for (int c = 0; c < 8; ++c) {
                short8 bf = bb[c * 64 + lane];   // read ONCE, feed two MFMAs
                acc0[c] = __builtin_amdgcn_mfma_f32_16x16x32_bf16(af0, bf, acc0[c], 0, 0, 0);
                acc1[c] = __builtin_amdgcn_mfma_f32_16x16x32_bf16(af1, bf, acc1[c], 0, 0, 0);
            }
            accl0 = __builtin_amdgcn_mfma_f32_16x16x32_bf16(af0, ones, accl0, 0, 0, 0);
            accl1 = __builtin_amdgcn_mfma_f32_16x16x32_bf16(af1, ones, accl1, 0, 0, 0);
        }
    }

    // epilogue. C/D layout: col = lane&15, row = (lane>>4)*4 + reg  [m89]
    float* Hpb = Hp + (size_t)kb * (NN * DD);
#pragma unroll
    for (int c = 0; c < 8; ++c)
#pragma unroll
        for (int r = 0; r < 4; ++r) {
            Hpb[(size_t)(rb + kg * 4 + r) * DD + c * 16 + n]      = acc0[c][r];
            Hpb[(size_t)(rb + 16 + kg * 4 + r) * DD + c * 16 + n] = acc1[c][r];
        }
    if (n == 0) {
        float* Lpb = Lp + (size_t)kb * NN;
#pragma unroll
        for (int r = 0; r < 4; ++r) {
            Lpb[rb + kg * 4 + r]      = accl0[r];
            Lpb[rb + 16 + kg * 4 + r] = accl1[r];
        }
    }
}

// ---------------- K4: combine split-K partials, normalize (float4) ----------------
// 262144 float4s total: 1024 blocks x 256 thr.
__global__ void k4_final(const float* __restrict__ Hp, const float* __restrict__ Lp,
                         float* __restrict__ out) {
    int g = blockIdx.x * 256 + threadIdx.x;   // 0..262143 float4s
    int i = g >> 5;                            // row
    float4 sv = make_float4(0.f, 0.f, 0.f, 0.f);
    float l = 0.f;
#pragma unroll
    for (int kb = 0; kb < 16; ++kb) {
        float4 v = *(const float4*)(Hp + (size_t)kb * (NN * DD) + (size_t)g * 4);
        sv.x += v.x; sv.y += v.y; sv.z += v.z; sv.w += v.w;
        l += Lp[(size_t)kb * NN + i];
    }
    float r = 1.f / l;
    *(float4*)(out + (size_t)g * 4) = make_float4(sv.x * r, sv.y * r, sv.z * r, sv.w * r);
}

extern "C" void kernel_launch(void* const* d_in, const int* in_sizes, int n_in,
                              void* d_out, int out_size, void* d_ws, size_t ws_size,
                              hipStream_t stream) {
    const int*   A  = (const int*)d_in[0];
    const float* X  = (const float*)d_in[1];
    const float* Ws = (const float*)d_in[2];
    const float* a  = (const float*)d_in[3];
    float* out = (float*)d_out;

    char* ws = (char*)d_ws;
    // Layout (~75.5 MB):
    //   [0, 8M)        Ap packed masks (uint4 per (row,kb,kg))
    //   [8M, 10M)      WhT bf16 [d][srcrow]
    //   [10M, +32K)    C1;  [+32K,+64K) C1s;  [+64K,+128K) E2 (float2)
    //   [11M, 75M)     Hp (16 split-K partials, 4MB each)
    //   [75M, +512K)   Lp (16 partials, 32KB each)
    uint4*  Ap  = (uint4*)(ws);
    ushort* WhT = (ushort*)(ws + (8u << 20));
    float*  C1  = (float*)(ws + (10u << 20));
    float*  C1s = (float*)(ws + (10u << 20) + (32u << 10));
    float2* E2  = (float2*)(ws + (10u << 20) + (64u << 10));
    float*  Hp  = (float*)(ws + (11u << 20));
    float*  Lp  = (float*)(ws + (75u << 20));

    k3a_pack<<<2048, 256, 0, stream>>>(A, Ap);
    k12_gemm<<<256, 256, 0, stream>>>(X, Ws, a, WhT, C1, C1s, E2);
    k3b_main<<<dim3(32, 16), 512, 0, stream>>>(Ap, WhT, C1, C1s, E2, Hp, Lp);
    k4_final<<<1024, 256, 0, stream>>>(Hp, Lp, out);
}

// Round 10
// 409.415 us; speedup vs baseline: 1.0042x; 1.0042x over previous
//
#include <hip/hip_runtime.h>
#include <hip/hip_bf16.h>

#define NN 8192
#define DD 128

typedef __attribute__((ext_vector_type(8))) short short8;
typedef __attribute__((ext_vector_type(4))) float f32x4;
typedef __attribute__((ext_vector_type(4))) int i32x4;
typedef unsigned int u32;
typedef unsigned long long u64;

__device__ __forceinline__ ushort f2bf(float f) {
    __hip_bfloat16 h = __float2bfloat16(f);
    return *(ushort*)&h;
}

// async 16B/lane global->LDS; LDS dest must be wave-uniform base + lane*16.
__device__ __forceinline__ void async_ld16(const void* g, void* l) {
    __builtin_amdgcn_global_load_lds(
        (const __attribute__((address_space(1))) u32*)g,
        (__attribute__((address_space(3))) u32*)l, 16, 0, 0);
}

#define PACK4(b, v, sh)                                     \
    b |= (u32)((v).x & 1) << (sh);                          \
    b |= (u32)((v).y & 1) << ((sh) + 1);                    \
    b |= (u32)((v).z & 1) << ((sh) + 2);                    \
    b |= (u32)((v).w & 1) << ((sh) + 3);

// ---------------- KA: merged {A bit-pack (2048 blocks) | k12 GEMM (256 blocks)} --
// Roles interleaved (bx%9==0 -> k12) so the HBM-bound A-stream and the
// compute-bound Wh GEMM run CONCURRENTLY across CUs instead of serially.
// Pack thread T -> (row=T>>6, kb=(T&63)>>2, kg=T&3): 16 8-col chunks
// k = kb*512 + kt*64 + tp*32 + kg*8 -> one uint4 (byte j = kt*2+tp, bit u).
__global__ __launch_bounds__(256) void kA_fused(const int* __restrict__ A,
                                                uint4* __restrict__ Ap,
                                                const float* __restrict__ X,
                                                const float* __restrict__ Ws,
                                                const float* __restrict__ a,
                                                ushort* __restrict__ WhT,
                                                float* __restrict__ C1,
                                                float* __restrict__ C1s,
                                                float2* __restrict__ E2) {
    __shared__ float lWs[128 * 132];   // [k][c] pad 132
    __shared__ float lX[32 * 132];     // [r][c] pad 132
    __shared__ ushort lT2[128 * 32];   // [c][r] bf16 transpose staging
    __shared__ float la[256];
    int t = threadIdx.x;
    int bxr = blockIdx.x;

    if (bxr % 9 != 0) {
        // ---- pack role ----
        u32 p = bxr - bxr / 9 - 1;            // 0..2047
        u32 T = p * 256 + t;                  // 0..524287
        u32 row = T >> 6, q = T & 63, kb = q >> 2, kg = q & 3;
        const int* base = A + (size_t)row * NN + kb * 512 + kg * 8;
        u32 d[4];
#pragma unroll
        for (int h = 0; h < 2; ++h) {         // kt 0..3 then 4..7
            i32x4 v[16];
#pragma unroll
            for (int j = 0; j < 8; ++j) {     // j = local (kt-4h)*2+tp
                int kt = h * 4 + (j >> 1), tp = j & 1;
                const int* pp = base + kt * 64 + tp * 32;
                v[j * 2]     = __builtin_nontemporal_load((const i32x4*)pp);
                v[j * 2 + 1] = __builtin_nontemporal_load((const i32x4*)(pp + 4));
            }
            u32 b01 = 0, b23 = 0;
#pragma unroll
            for (int j = 0; j < 8; ++j) {
                u32 b = 0;
                PACK4(b, v[j * 2], 0);
                PACK4(b, v[j * 2 + 1], 4);
                if (j < 4) b01 |= b << (8 * j);
                else       b23 |= b << (8 * (j - 4));
            }
            d[h * 2] = b01; d[h * 2 + 1] = b23;
        }
        Ap[T] = make_uint4(d[0], d[1], d[2], d[3]);
        return;
    }

    // ---- k12 role: Wh = X @ Ws + per-row scalars + bf16 transpose ----
    int bx = bxr / 9;                          // 0..255
    la[t] = a[t];
    const float4* Ws4 = (const float4*)Ws;
    const float4* X4 = (const float4*)X;
    for (int j = 0; j < 16; ++j) {
        int u = j * 256 + t;
        int k = u >> 5, c4 = u & 31;
        *(float4*)&lWs[k * 132 + c4 * 4] = Ws4[u];
    }
    for (int j = 0; j < 4; ++j) {
        int u = j * 256 + t;
        int r = u >> 5, c4 = u & 31;
        *(float4*)&lX[r * 132 + c4 * 4] = X4[bx * 1024 + u];
    }
    __syncthreads();
    int r0 = (t >> 5) * 4, c0 = (t & 31) * 4;
    float acc[4][4];
#pragma unroll
    for (int i = 0; i < 4; ++i)
#pragma unroll
        for (int j = 0; j < 4; ++j) acc[i][j] = 0.f;
#pragma unroll 4
    for (int k = 0; k < 128; ++k) {
        float4 wv = *(const float4*)&lWs[k * 132 + c0];
        float x0 = lX[(r0 + 0) * 132 + k];
        float x1 = lX[(r0 + 1) * 132 + k];
        float x2 = lX[(r0 + 2) * 132 + k];
        float x3 = lX[(r0 + 3) * 132 + k];
#pragma unroll
        for (int j = 0; j < 4; ++j) {
            acc[0][j] += x0 * ((const float*)&wv)[j];
            acc[1][j] += x1 * ((const float*)&wv)[j];
            acc[2][j] += x2 * ((const float*)&wv)[j];
            acc[3][j] += x3 * ((const float*)&wv)[j];
        }
    }
#pragma unroll
    for (int i = 0; i < 4; ++i)
#pragma unroll
        for (int j = 0; j < 4; ++j)
            lT2[(c0 + j) * 32 + r0 + i] = f2bf(acc[i][j]);
    float p1[4], p2[4];
#pragma unroll
    for (int i = 0; i < 4; ++i) {
        p1[i] = 0.f; p2[i] = 0.f;
#pragma unroll
        for (int j = 0; j < 4; ++j) {
            p1[i] += acc[i][j] * la[c0 + j];
            p2[i] += acc[i][j] * la[128 + c0 + j];
        }
    }
#pragma unroll
    for (int m = 1; m < 32; m <<= 1) {
#pragma unroll
        for (int i = 0; i < 4; ++i) {
            p1[i] += __shfl_xor(p1[i], m);
            p2[i] += __shfl_xor(p2[i], m);
        }
    }
    if ((t & 31) == 0) {
#pragma unroll
        for (int i = 0; i < 4; ++i) {
            int row = bx * 32 + r0 + i;
            C1[row]  = __expf(p1[i]);
            C1s[row] = __expf(0.2f * p1[i]);
            E2[row]  = make_float2(__expf(p2[i]), __expf(0.2f * p2[i]));
        }
    }
    __syncthreads();
    {
        int d = t >> 1, hf = t & 1;
        uint4* dst = (uint4*)&WhT[(size_t)d * NN + bx * 32 + hf * 16];
        const uint4* src = (const uint4*)&lT2[d * 32 + hf * 16];
        dst[0] = src[0];
        dst[1] = src[1];
    }
}

// ---------------- K3b: masked-softmax GEMM, 1024-k per block in two halves -------
// grid (32 rowblocks, 8 ksplit) x 512 thr (8 waves x 32 rows) = 256 blocks
// = exactly 1/CU, single residency round. Halved ksplit halves Hp traffic
// (64->32 MB each way). Per half: B-slice (128 KB) restaged, E (8 KB, both
// halves) staged once; masks = 4 uint4 REGISTERS/lane loaded in prologue.
// Compute phases are pure {VALU af-build, ds_read B, MFMA}.
__global__ __launch_bounds__(512, 2) void k3b_main(
    const uint4* __restrict__ Ap, const ushort* __restrict__ WhT,
    const float* __restrict__ C1, const float* __restrict__ C1s,
    const float2* __restrict__ E2,
    float* __restrict__ Hp, float* __restrict__ Lp) {

    __shared__ __align__(16) char lB[131072];      // [p = kt*16+tp*8+c][lane*16]
    __shared__ __align__(16) char lE[8192];        // float2 E for 1024 k

    int tid = threadIdx.x;
    int lane = tid & 63;
    int w = tid >> 6;           // 8 waves
    int n = lane & 15;
    int kg = lane >> 4;

    int bx = blockIdx.x;        // 32 row-blocks (256 rows each)
    int kb = blockIdx.y;        // 8 k-splits (1024 k each)
    int rb = bx * 256 + w * 32; // wave's 32 rows (two 16-row groups)

    float c1_0 = C1[rb + n],      c1s_0 = C1s[rb + n];
    float c1_1 = C1[rb + 16 + n], c1s_1 = C1s[rb + 16 + n];

    // masks: 512-k slice s = kb*2+h; rows rb+n (grp0), rb+16+n (grp1)
    uint4 Mq0[2], Mq1[2];
#pragma unroll
    for (int h = 0; h < 2; ++h) {
        Mq0[h] = Ap[(size_t)(rb + n) * 64 + (kb * 2 + h) * 4 + kg];
        Mq1[h] = Ap[(size_t)(rb + 16 + n) * 64 + (kb * 2 + h) * 4 + kg];
    }

    // stage B half 0 (128 fragments x 1 KB) -- wave w stages p = w+8i
#pragma unroll
    for (int i = 0; i < 16; ++i) {
        int p = w + i * 8;
        int kt = p >> 4, tp = (p >> 3) & 1, c = p & 7;
        const ushort* src = WhT + (size_t)(c * 16 + n) * NN +
                            (size_t)kb * 1024 + kt * 64 + tp * 32 + kg * 8;
        async_ld16(src, lB + p * 1024 + lane * 16);
    }
    // stage E for BOTH halves (8 KB) once
    if (w == 0)
#pragma unroll
        for (int i = 0; i < 8; ++i)
            async_ld16((const char*)(E2 + (size_t)kb * 1024) + (i * 64 + lane) * 16,
                       lE + (i * 64 + lane) * 16);

    short8 ones;
#pragma unroll
    for (int j = 0; j < 8; ++j) ones[j] = (short)0x3F80;  // bf16 1.0

    f32x4 acc0[8], acc1[8];
#pragma unroll
    for (int c = 0; c < 8; ++c) {
        acc0[c] = (f32x4){0.f, 0.f, 0.f, 0.f};
        acc1[c] = (f32x4){0.f, 0.f, 0.f, 0.f};
    }
    f32x4 accl0 = (f32x4){0.f, 0.f, 0.f, 0.f};
    f32x4 accl1 = (f32x4){0.f, 0.f, 0.f, 0.f};

    __syncthreads();   // B(h0)/E resident

#pragma unroll
    for (int h = 0; h < 2; ++h) {
        if (h == 1) {
            __syncthreads();   // all waves done reading B(h0)
#pragma unroll
            for (int i = 0; i < 16; ++i) {
                int p = w + i * 8;
                int kt = p >> 4, tp = (p >> 3) & 1, c = p & 7;
                const ushort* src = WhT + (size_t)(c * 16 + n) * NN +
                                    (size_t)kb * 1024 + 512 + kt * 64 + tp * 32 + kg * 8;
                async_ld16(src, lB + p * 1024 + lane * 16);
            }
            __syncthreads();   // B(h1) resident
        }
#pragma unroll
        for (int kt = 0; kt < 8; ++kt) {
#pragma unroll
            for (int tp = 0; tp < 2; ++tp) {
                const int j = kt * 2 + tp;   // compile-time byte index
                u32 d0 = (j < 4) ? Mq0[h].x : (j < 8) ? Mq0[h].y : (j < 12) ? Mq0[h].z : Mq0[h].w;
                u32 d1 = (j < 4) ? Mq1[h].x : (j < 8) ? Mq1[h].y : (j < 12) ? Mq1[h].z : Mq1[h].w;
                u32 ab0 = (d0 >> ((j & 3) * 8)) & 0xffu;
                u32 ab1 = (d1 >> ((j & 3) * 8)) & 0xffu;

                const float4* ev = (const float4*)((const float*)lE +
                                                   (h * 512 + kt * 64 + tp * 32 + kg * 8) * 2);
                float pe[16];
                *(float4*)(pe + 0)  = ev[0];
                *(float4*)(pe + 4)  = ev[1];
                *(float4*)(pe + 8)  = ev[2];
                *(float4*)(pe + 12) = ev[3];
                short8 af0, af1;
#pragma unroll
                for (int u = 0; u < 8; ++u) {
                    // exp(leaky(s1+s2)) = max(e^s1 e^s2, e^.2s1 e^.2s2)
                    float w0 = fmaxf(c1_0 * pe[2 * u], c1s_0 * pe[2 * u + 1]);
                    float w1 = fmaxf(c1_1 * pe[2 * u], c1s_1 * pe[2 * u + 1]);
                    af0[u] = ((ab0 >> u) & 1u) ? (short)f2bf(w0) : (short)0;
                    af1[u] = ((ab1 >> u) & 1u) ? (short)f2bf(w1) : (short)0;
                }
                const short8* bb = (const short8*)(lB + (kt * 16 + tp * 8) * 1024);
#pragma unroll
                for (int c = 0; c < 8; ++c) {
                    short8 bf = bb[c * 64 + lane];   // read ONCE, feed two MFMAs
                    acc0[c] = __builtin_amdgcn_mfma_f32_16x16x32_bf16(af0, bf, acc0[c], 0, 0, 0);
                    acc1[c] = __builtin_amdgcn_mfma_f32_16x16x32_bf16(af1, bf, acc1[c], 0, 0, 0);
                }
                accl0 = __builtin_amdgcn_mfma_f32_16x16x32_bf16(af0, ones, accl0, 0, 0, 0);
                accl1 = __builtin_amdgcn_mfma_f32_16x16x32_bf16(af1, ones, accl1, 0, 0, 0);
            }
        }
    }

    // epilogue. C/D layout: col = lane&15, row = (lane>>4)*4 + reg  [m89]
    float* Hpb = Hp + (size_t)kb * (NN * DD);
#pragma unroll
    for (int c = 0; c < 8; ++c)
#pragma unroll
        for (int r = 0; r < 4; ++r) {
            Hpb[(size_t)(rb + kg * 4 + r) * DD + c * 16 + n]      = acc0[c][r];
            Hpb[(size_t)(rb + 16 + kg * 4 + r) * DD + c * 16 + n] = acc1[c][r];
        }
    if (n == 0) {
        float* Lpb = Lp + (size_t)kb * NN;
#pragma unroll
        for (int r = 0; r < 4; ++r) {
            Lpb[rb + kg * 4 + r]      = accl0[r];
            Lpb[rb + 16 + kg * 4 + r] = accl1[r];
        }
    }
}

// ---------------- K4: combine 8 split-K partials, normalize (float4) -------------
// 262144 float4s total: 1024 blocks x 256 thr.
__global__ void k4_final(const float* __restrict__ Hp, const float* __restrict__ Lp,
                         float* __restrict__ out) {
    int g = blockIdx.x * 256 + threadIdx.x;   // 0..262143 float4s
    int i = g >> 5;                            // row
    float4 sv = make_float4(0.f, 0.f, 0.f, 0.f);
    float l = 0.f;
#pragma unroll
    for (int kb = 0; kb < 8; ++kb) {
        float4 v = *(const float4*)(Hp + (size_t)kb * (NN * DD) + (size_t)g * 4);
        sv.x += v.x; sv.y += v.y; sv.z += v.z; sv.w += v.w;
        l += Lp[(size_t)kb * NN + i];
    }
    float r = 1.f / l;
    *(float4*)(out + (size_t)g * 4) = make_float4(sv.x * r, sv.y * r, sv.z * r, sv.w * r);
}

extern "C" void kernel_launch(void* const* d_in, const int* in_sizes, int n_in,
                              void* d_out, int out_size, void* d_ws, size_t ws_size,
                              hipStream_t stream) {
    const int*   A  = (const int*)d_in[0];
    const float* X  = (const float*)d_in[1];
    const float* Ws = (const float*)d_in[2];
    const float* a  = (const float*)d_in[3];
    float* out = (float*)d_out;

    char* ws = (char*)d_ws;
    // Layout (~43.3 MB):
    //   [0, 8M)        Ap packed masks (uint4 per (row, 512k-slice, kg))
    //   [8M, 10M)      WhT bf16 [d][srcrow]
    //   [10M, +32K)    C1;  [+32K,+64K) C1s;  [+64K,+128K) E2 (float2)
    //   [11M, 43M)     Hp (8 split-K partials, 4MB each)
    //   [43M, +256K)   Lp (8 partials, 32KB each)
    uint4*  Ap  = (uint4*)(ws);
    ushort* WhT = (ushort*)(ws + (8u << 20));
    float*  C1  = (float*)(ws + (10u << 20));
    float*  C1s = (float*)(ws + (10u << 20) + (32u << 10));
    float2* E2  = (float2*)(ws + (10u << 20) + (64u << 10));
    float*  Hp  = (float*)(ws + (11u << 20));
    float*  Lp  = (float*)(ws + (43u << 20));

    kA_fused<<<2304, 256, 0, stream>>>(A, Ap, X, Ws, a, WhT, C1, C1s, E2);
    k3b_main<<<dim3(32, 8), 512, 0, stream>>>(Ap, WhT, C1, C1s, E2, Hp, Lp);
    k4_final<<<1024, 256, 0, stream>>>(Hp, Lp, out);
}